// Round 17
// baseline (230.267 us; speedup 1.0000x reference)
//
#include <hip/hip_runtime.h>
#include <hip/hip_bf16.h>
#include <cstdint>
#include <cstddef>

// Problem constants (fixed shapes)
#define Bn   4
#define Sn   4096
#define Nn   16384
#define CSn  256
#define COn  128
#define CINn 384
#define MTOT 65536   // B*N

using short8 = short __attribute__((ext_vector_type(8)));
using f32x4  = float __attribute__((ext_vector_type(4)));

static __device__ __forceinline__ float bf2f(unsigned short u){
  unsigned int x = ((unsigned int)u) << 16;
  return __builtin_bit_cast(float, x);
}
static __device__ __forceinline__ unsigned short f2bf(float f){
  unsigned int x = __builtin_bit_cast(unsigned int, f);
  x += 0x7fffu + ((x >> 16) & 1u);   // RNE
  return (unsigned short)(x >> 16);
}

// ---------------- KNN ----------------
static __device__ __forceinline__ void top3_insert(float d, int s,
    float& d0, float& d1, float& d2, int& i0, int& i1, int& i2){
  if (d < d2){
    if (d < d1){
      d2 = d1; i2 = i1;
      if (d < d0){ d1 = d0; i1 = i0; d0 = d; i0 = s; }
      else       { d1 = d;  i1 = s; }
    } else { d2 = d; i2 = s; }
  }
}

// Q=2 KNN: 2048 blocks x 128 threads (2 waves), wave-independent, no barriers.
// Block = 128 queries (thread owns gq0=lane and gq1=lane+64) x one slice-pair;
// wave w scans slice spair*2+w (512 keys ascending). ONE broadcast
// ds_read_b128 per key now feeds TWO independent 16-instr asm chains (the
// R12-proven block duplicated verbatim, separate state, no packing glue):
// halves LDS-pipe load per pair and gives ILP=2 on the serial top-3 chain.
// Dist bit-identical to reference; strict '<' + ascending slices -> top_k
// tie-break exact. Partials to PD/PI; knnmerge merges 8 slices ascending.
__global__ __launch_bounds__(128) void knn_kernel(
    const float* __restrict__ sxyz, const float* __restrict__ oxyz,
    float* __restrict__ PD, int* __restrict__ PI)
{
  __shared__ float4 cb[2][2][64];   // 4 KB: [wave][dbuf][key]

  const int b     = blockIdx.x >> 9;       // 512 blocks per batch
  const int rem   = blockIdx.x & 511;
  const int qblk  = rem >> 2;              // 0..127 (128 queries each)
  const int spair = rem & 3;               // 0..3
  const int lane  = threadIdx.x & 63;
  const int wave  = threadIdx.x >> 6;      // 0..1
  const int gq0   = b*Nn + qblk*128 + lane;
  const int gq1   = gq0 + 64;
  const float* op0 = oxyz + (size_t)gq0*3;
  const float* op1 = oxyz + (size_t)gq1*3;
  const float pxA = op0[0], pyA = op0[1], pzA = op0[2];
  const float pxB = op1[0], pyB = op1[1], pzB = op1[2];
  const float qqA = __fadd_rn(__fadd_rn(__fmul_rn(pxA,pxA), __fmul_rn(pyA,pyA)), __fmul_rn(pzA,pzA));
  const float qqB = __fadd_rn(__fadd_rn(__fmul_rn(pxB,pxB), __fmul_rn(pyB,pyB)), __fmul_rn(pzB,pzB));

  const float* sx = sxyz + (size_t)b*Sn*3;
  const int slice = spair*2 + wave;        // 0..7, ascending key ranges
  const int sbase = slice*512;             // this wave's 512-key chain

  float ax, ay, az;
  {
    int j = sbase + lane;
    ax=sx[j*3+0]; ay=sx[j*3+1]; az=sx[j*3+2];
  }
  {
    float ssv = __fadd_rn(__fadd_rn(__fmul_rn(ax,ax), __fmul_rn(ay,ay)), __fmul_rn(az,az));
    cb[wave][0][lane] = make_float4(ax, ay, az, ssv);
  }

  float dA0=3.4e38f, dA1=3.4e38f, dA2=3.4e38f;
  int   iA0=0, iA1=0, iA2=0;
  float dB0=3.4e38f, dB1=3.4e38f, dB2=3.4e38f;
  int   iB0=0, iB1=0, iB2=0;

  int cur = 0;
  for (int c = 0; c < 8; ++c){
    if (c < 7){                          // next chunk's loads EARLY
      int j = sbase + (c+1)*64 + lane;
      ax=sx[j*3+0]; ay=sx[j*3+1]; az=sx[j*3+2];
    }
    const int base = sbase + c*64;
    #pragma unroll 8
    for (int i = 0; i < 64; ++i){
      float4 k = cb[wave][cur][i];       // broadcast ds_read_b128 (shared by both queries)
      const int idx = base + i;
      {
        float t, u; int t2;
        unsigned long long c0, c1, c2;
        asm("v_mul_f32 %[t], %[kx], %[px]\n\t"
            "v_fma_f32 %[t], %[ky], %[py], %[t]\n\t"
            "v_fma_f32 %[t], %[kz], %[pz], %[t]\n\t"
            "v_add_f32 %[u], %[qq], %[ss]\n\t"
            "v_fma_f32 %[u], -2.0, %[t], %[u]\n\t"
            "v_cmp_lt_f32 %[c0], %[u], %[d0]\n\t"
            "v_cmp_lt_f32 %[c1], %[u], %[d1]\n\t"
            "v_cmp_lt_f32 %[c2], %[u], %[d2]\n\t"
            "v_med3_f32 %[d2], %[u], %[d1], %[d2]\n\t"
            "v_med3_f32 %[d1], %[u], %[d0], %[d1]\n\t"
            "v_min_f32  %[d0], %[u], %[d0]\n\t"
            "v_cndmask_b32 %[t2], %[idx], %[i1], %[c1]\n\t"
            "v_cndmask_b32 %[i2], %[i2], %[t2], %[c2]\n\t"
            "v_cndmask_b32 %[t2], %[idx], %[i0], %[c0]\n\t"
            "v_cndmask_b32 %[i1], %[i1], %[t2], %[c1]\n\t"
            "v_cndmask_b32 %[i0], %[i0], %[idx], %[c0]"
            : [d0]"+v"(dA0), [d1]"+v"(dA1), [d2]"+v"(dA2),
              [i0]"+v"(iA0), [i1]"+v"(iA1), [i2]"+v"(iA2),
              [t]"=&v"(t), [u]"=&v"(u), [t2]"=&v"(t2),
              [c0]"=&s"(c0), [c1]"=&s"(c1), [c2]"=&s"(c2)
            : [kx]"v"(k.x), [ky]"v"(k.y), [kz]"v"(k.z), [ss]"v"(k.w),
              [px]"v"(pxA), [py]"v"(pyA), [pz]"v"(pzA), [qq]"v"(qqA),
              [idx]"v"(idx));
      }
      {
        float t, u; int t2;
        unsigned long long c0, c1, c2;
        asm("v_mul_f32 %[t], %[kx], %[px]\n\t"
            "v_fma_f32 %[t], %[ky], %[py], %[t]\n\t"
            "v_fma_f32 %[t], %[kz], %[pz], %[t]\n\t"
            "v_add_f32 %[u], %[qq], %[ss]\n\t"
            "v_fma_f32 %[u], -2.0, %[t], %[u]\n\t"
            "v_cmp_lt_f32 %[c0], %[u], %[d0]\n\t"
            "v_cmp_lt_f32 %[c1], %[u], %[d1]\n\t"
            "v_cmp_lt_f32 %[c2], %[u], %[d2]\n\t"
            "v_med3_f32 %[d2], %[u], %[d1], %[d2]\n\t"
            "v_med3_f32 %[d1], %[u], %[d0], %[d1]\n\t"
            "v_min_f32  %[d0], %[u], %[d0]\n\t"
            "v_cndmask_b32 %[t2], %[idx], %[i1], %[c1]\n\t"
            "v_cndmask_b32 %[i2], %[i2], %[t2], %[c2]\n\t"
            "v_cndmask_b32 %[t2], %[idx], %[i0], %[c0]\n\t"
            "v_cndmask_b32 %[i1], %[i1], %[t2], %[c1]\n\t"
            "v_cndmask_b32 %[i0], %[i0], %[idx], %[c0]"
            : [d0]"+v"(dB0), [d1]"+v"(dB1), [d2]"+v"(dB2),
              [i0]"+v"(iB0), [i1]"+v"(iB1), [i2]"+v"(iB2),
              [t]"=&v"(t), [u]"=&v"(u), [t2]"=&v"(t2),
              [c0]"=&s"(c0), [c1]"=&s"(c1), [c2]"=&s"(c2)
            : [kx]"v"(k.x), [ky]"v"(k.y), [kz]"v"(k.z), [ss]"v"(k.w),
              [px]"v"(pxB), [py]"v"(pyB), [pz]"v"(pzB), [qq]"v"(qqB),
              [idx]"v"(idx));
      }
    }
    if (c < 7){                          // write next chunk AFTER the scan
      int nxt = cur ^ 1;
      float ssv = __fadd_rn(__fadd_rn(__fmul_rn(ax,ax), __fmul_rn(ay,ay)), __fmul_rn(az,az));
      cb[wave][nxt][lane] = make_float4(ax, ay, az, ssv);
      cur = nxt;
    }
  }

  PD[(slice*3+0)*MTOT + gq0] = dA0;
  PD[(slice*3+1)*MTOT + gq0] = dA1;
  PD[(slice*3+2)*MTOT + gq0] = dA2;
  PI[(slice*3+0)*MTOT + gq0] = iA0;
  PI[(slice*3+1)*MTOT + gq0] = iA1;
  PI[(slice*3+2)*MTOT + gq0] = iA2;
  PD[(slice*3+0)*MTOT + gq1] = dB0;
  PD[(slice*3+1)*MTOT + gq1] = dB1;
  PD[(slice*3+2)*MTOT + gq1] = dB2;
  PI[(slice*3+0)*MTOT + gq1] = iB0;
  PI[(slice*3+1)*MTOT + gq1] = iB1;
  PI[(slice*3+2)*MTOT + gq1] = iB2;
}

// merge 8 slice-partials per query (ascending slice = ascending key range,
// strict '<' => reference top_k tie-break), compute weights, write kw/ki.
__global__ __launch_bounds__(256) void knnmerge_kernel(
    const float* __restrict__ PD, const int* __restrict__ PI,
    float* __restrict__ kw, int* __restrict__ ki)
{
  const int gq = blockIdx.x*256 + threadIdx.x;   // 0..65535
  float e0=3.4e38f, e1=3.4e38f, e2=3.4e38f;
  int   j0=0, j1=0, j2=0;
  #pragma unroll
  for (int s = 0; s < 8; ++s){
    #pragma unroll
    for (int j = 0; j < 3; ++j){
      float d = PD[(s*3+j)*MTOT + gq];
      int   i = PI[(s*3+j)*MTOT + gq];
      top3_insert(d, i, e0,e1,e2, j0,j1,j2);
    }
  }
  float wa = 1.0f/(e0+1e-8f), wb = 1.0f/(e1+1e-8f), wc = 1.0f/(e2+1e-8f);
  float sm = __fadd_rn(__fadd_rn(wa, wb), wc);
  size_t base = (size_t)gq*3;
  kw[base+0] = wa/sm; kw[base+1] = wb/sm; kw[base+2] = wc/sm;
  ki[base+0] = j0;    ki[base+1] = j1;    ki[base+2] = j2;
}

// ------------- fp32 -> bf16 weight conversion -------------
__global__ __launch_bounds__(256) void cvtw_kernel(
    const float* __restrict__ w0, const float* __restrict__ w1,
    unsigned short* __restrict__ w0b, unsigned short* __restrict__ w1b)
{
  int i = blockIdx.x*256 + threadIdx.x;
  if (i < 256*384) w0b[i] = f2bf(w0[i]);
  int j = i - 256*384;
  if (j >= 0 && j < 256*256) w1b[j] = f2bf(w1[j]);
}

// ------------- GEMM: Y[M][256] = A[M][KDIM] @ W[256][KDIM]^T + bias ----------
// R13-proven. BM=128, BN=256, BK=64; 4 waves (wave w owns cols [w*64,+64)).
// AFUSE (gemm0): A staged on the fly (kw/ki from LDS, fp32 sfeat gathers):
//   k <  128: A[m][k] = f2bf(ofeat[m][k])
//   k >= 128: A[m][k] = f2bf(fma(w2,s2, fma(w1,s1, mul(w0,s0))))
// BNRELU (gemm1): BN0 scale/shift in-kernel from gemm0 stats, A'=relu(A*sc+sh).
// Epilogue: bf16 store + per-channel sum/sumsq atomics for BN stats.
template<int KDIM, bool BNRELU, bool AFUSE>
__global__ __launch_bounds__(256) void gemm_kernel(
    const unsigned short* __restrict__ A,
    const unsigned short* __restrict__ W,
    const float* __restrict__ bias,
    const float* __restrict__ s0sum,
    const float* __restrict__ s0sq,
    const float* __restrict__ bng,
    const float* __restrict__ bnbt,
    const float* __restrict__ kwg,
    const int*   __restrict__ kig,
    const float* __restrict__ sfeat,
    const float* __restrict__ ofeat,
    unsigned short* __restrict__ Y,
    float* __restrict__ osum,
    float* __restrict__ osq)
{
  __shared__ unsigned short As[128*64];   // 16 KB, XOR-swizzled 16B chunks
  __shared__ unsigned short Bs[256*64];   // 32 KB
  __shared__ float lsc[256], lsh[256];    // BNRELU only
  __shared__ float lkw[128][3];           // AFUSE only
  __shared__ int   lki[128][3];
  const int tid  = threadIdx.x;
  const int lane = tid & 63;
  const int wave = tid >> 6;
  const size_t mbase = (size_t)blockIdx.x * 128;
  if constexpr (BNRELU){
    float mean = s0sum[tid] * (1.0f/65536.0f);
    float var  = s0sq[tid] * (1.0f/65536.0f) - mean*mean;
    float s = bng[tid] / sqrtf(var + 1e-5f);
    lsc[tid] = s;
    lsh[tid] = __fmaf_rn(-mean, s, bnbt[tid]);
  }
  if constexpr (AFUSE){
    float* lkwf = &lkw[0][0];
    int*   lkif = &lki[0][0];
    for (int t = tid; t < 384; t += 256){
      lkwf[t] = kwg[mbase*3 + t];
      lkif[t] = kig[mbase*3 + t];
    }
  }
  f32x4 acc[8][4];
  #pragma unroll
  for (int m2 = 0; m2 < 8; ++m2)
    #pragma unroll
    for (int n2 = 0; n2 < 4; ++n2) acc[m2][n2] = f32x4{0.f,0.f,0.f,0.f};
  __syncthreads();

  for (int k0 = 0; k0 < KDIM; k0 += 64){
    if (k0) __syncthreads();
    // stage A: 128 rows x 8 chunks(16B) = 1024 chunks, 4/thread
    #pragma unroll
    for (int i = 0; i < 4; ++i){
      int cid = tid + 256*i;
      int row = cid >> 3, c8 = cid & 7;
      short8 v;
      if constexpr (AFUSE){
        const int m = (int)mbase + row;
        const int k = k0 + c8*8;
        float vals[8];
        if (k < COn){
          const float4* p = reinterpret_cast<const float4*>(ofeat + (size_t)m*COn + k);
          float4 u0 = p[0], u1 = p[1];
          vals[0]=u0.x; vals[1]=u0.y; vals[2]=u0.z; vals[3]=u0.w;
          vals[4]=u1.x; vals[5]=u1.y; vals[6]=u1.z; vals[7]=u1.w;
        } else {
          const int cc = k - COn;
          const int bb = m >> 14;
          const float* sb = sfeat + (size_t)bb*Sn*CSn;
          const float w0v = lkw[row][0], w1v = lkw[row][1], w2v = lkw[row][2];
          const int   i0  = lki[row][0], i1  = lki[row][1], i2  = lki[row][2];
          const float4* p0 = reinterpret_cast<const float4*>(sb + (size_t)i0*CSn + cc);
          const float4* p1 = reinterpret_cast<const float4*>(sb + (size_t)i1*CSn + cc);
          const float4* p2 = reinterpret_cast<const float4*>(sb + (size_t)i2*CSn + cc);
          float4 a0 = p0[0], a1 = p0[1];
          float4 b0v = p1[0], b1v = p1[1];
          float4 c0v = p2[0], c1v = p2[1];
          float s0[8] = {a0.x,a0.y,a0.z,a0.w,a1.x,a1.y,a1.z,a1.w};
          float s1[8] = {b0v.x,b0v.y,b0v.z,b0v.w,b1v.x,b1v.y,b1v.z,b1v.w};
          float s2[8] = {c0v.x,c0v.y,c0v.z,c0v.w,c1v.x,c1v.y,c1v.z,c1v.w};
          #pragma unroll
          for (int j = 0; j < 8; ++j)
            vals[j] = __fmaf_rn(w2v, s2[j], __fmaf_rn(w1v, s1[j], __fmul_rn(w0v, s0[j])));
        }
        #pragma unroll
        for (int j = 0; j < 8; ++j) v[j] = (short)f2bf(vals[j]);
      } else {
        v = *reinterpret_cast<const short8*>(A + (mbase+row)*KDIM + k0 + c8*8);
        if constexpr (BNRELU){
          #pragma unroll
          for (int j = 0; j < 8; ++j){
            int kc = k0 + c8*8 + j;
            float f = bf2f((unsigned short)v[j]);
            f = fmaxf(__fmaf_rn(f, lsc[kc], lsh[kc]), 0.0f);
            v[j] = (short)f2bf(f);
          }
        }
      }
      *reinterpret_cast<short8*>(reinterpret_cast<char*>(As) + row*128 + ((c8 ^ (row&7)) << 4)) = v;
    }
    // stage B (weights): 256 rows x 8 chunks = 2048 chunks, 8/thread
    #pragma unroll
    for (int i = 0; i < 8; ++i){
      int cid = tid + 256*i;
      int row = cid >> 3, c8 = cid & 7;
      short8 v = *reinterpret_cast<const short8*>(W + (size_t)row*KDIM + k0 + c8*8);
      *reinterpret_cast<short8*>(reinterpret_cast<char*>(Bs) + row*128 + ((c8 ^ (row&7)) << 4)) = v;
    }
    __syncthreads();
    #pragma unroll
    for (int kk = 0; kk < 2; ++kk){
      short8 af[8], bv[4];
      #pragma unroll
      for (int m2 = 0; m2 < 8; ++m2){
        int row = m2*16 + (lane & 15);
        int c8  = kk*4 + (lane >> 4);
        af[m2] = *reinterpret_cast<const short8*>(reinterpret_cast<char*>(As) + row*128 + ((c8 ^ (row&7)) << 4));
      }
      #pragma unroll
      for (int n2 = 0; n2 < 4; ++n2){
        int row = wave*64 + n2*16 + (lane & 15);
        int c8  = kk*4 + (lane >> 4);
        bv[n2] = *reinterpret_cast<const short8*>(reinterpret_cast<char*>(Bs) + row*128 + ((c8 ^ (row&7)) << 4));
      }
      #pragma unroll
      for (int m2 = 0; m2 < 8; ++m2)
        #pragma unroll
        for (int n2 = 0; n2 < 4; ++n2)
          acc[m2][n2] = __builtin_amdgcn_mfma_f32_16x16x32_bf16(af[m2], bv[n2], acc[m2][n2], 0, 0, 0);
    }
  }

  // epilogue: C/D layout col = lane&15, row = (lane>>4)*4 + j  [m89-verified]
  const int colg0 = wave*64;
  float spart[4] = {0,0,0,0}, qpart[4] = {0,0,0,0};
  #pragma unroll
  for (int m2 = 0; m2 < 8; ++m2){
    #pragma unroll
    for (int n2 = 0; n2 < 4; ++n2){
      const int gc  = colg0 + n2*16 + (lane & 15);
      const float bvv = bias[gc];
      #pragma unroll
      for (int j = 0; j < 4; ++j){
        float yv = acc[m2][n2][j] + bvv;
        size_t gr = mbase + m2*16 + (lane>>4)*4 + j;
        Y[gr*256 + gc] = f2bf(yv);
        spart[n2] += yv;
        qpart[n2] = __fmaf_rn(yv, yv, qpart[n2]);
      }
    }
  }
  #pragma unroll
  for (int n2 = 0; n2 < 4; ++n2){
    float s = spart[n2], q = qpart[n2];
    s += __shfl_xor(s, 16); q += __shfl_xor(q, 16);
    s += __shfl_xor(s, 32); q += __shfl_xor(q, 32);
    if (lane < 16){
      int gc = colg0 + n2*16 + lane;
      atomicAdd(&osum[gc], s);
      atomicAdd(&osq[gc], q);
    }
  }
}

// ------------- final BN1 + ReLU -> fp32 out (BN finalize folded in) -------------
__global__ __launch_bounds__(256) void apply_kernel(
    const unsigned short* __restrict__ y,
    const float* __restrict__ s1sum, const float* __restrict__ s1sq,
    const float* __restrict__ g, const float* __restrict__ bt,
    float* __restrict__ out)
{
  __shared__ float ssc[256], ssh[256];
  {
    int c = threadIdx.x;
    float mean = s1sum[c] * (1.0f/65536.0f);
    float var  = s1sq[c] * (1.0f/65536.0f) - mean*mean;
    float s = g[c] / sqrtf(var + 1e-5f);
    ssc[c] = s;
    ssh[c] = __fmaf_rn(-mean, s, bt[c]);
  }
  __syncthreads();
  const int t = blockIdx.x*256 + threadIdx.x;
  const size_t base = (size_t)t * 8;
  const int c0 = (int)(base & 255);
  short8 v = *reinterpret_cast<const short8*>(y + base);
  float r[8];
  #pragma unroll
  for (int j = 0; j < 8; ++j){
    float f = bf2f((unsigned short)v[j]);
    f = __fmaf_rn(f, ssc[c0+j], ssh[c0+j]);
    r[j] = fmaxf(f, 0.0f);
  }
  float4 o0, o1;
  o0.x=r[0]; o0.y=r[1]; o0.z=r[2]; o0.w=r[3];
  o1.x=r[4]; o1.y=r[5]; o1.z=r[6]; o1.w=r[7];
  *reinterpret_cast<float4*>(out + base)     = o0;
  *reinterpret_cast<float4*>(out + base + 4) = o1;
}

// ---------------- workspace layout ----------------
constexpr size_t WS_STATS = 0;                                  // 4*256 f32
constexpr size_t WS_W0B   = 8192;                               // 98304 bf16
constexpr size_t WS_W1B   = WS_W0B + 196608;                    // 65536 bf16
constexpr size_t WS_KW    = WS_W1B + 131072;                    // M*3 f32
constexpr size_t WS_KI    = WS_KW + 786432;                     // M*3 i32
constexpr size_t WS_BIG   = 4194304;                            // big region
constexpr size_t WS_Y0    = WS_BIG + (size_t)MTOT*CINn*2;       // M*256 bf16
// PD/PI (6.3 MB each) at BIG start; dead after knnmerge. Y1 reuses BIG start.
constexpr size_t WS_PD    = WS_BIG;
constexpr size_t WS_PI    = WS_BIG + (size_t)8*3*MTOT*4;

extern "C" void kernel_launch(void* const* d_in, const int* in_sizes, int n_in,
                              void* d_out, int out_size, void* d_ws, size_t ws_size,
                              hipStream_t stream)
{
  const float* sxyz  = (const float*)d_in[0];
  const float* sfeat = (const float*)d_in[1];
  const float* oxyz  = (const float*)d_in[2];
  const float* ofeat = (const float*)d_in[3];
  const float* w0    = (const float*)d_in[4];
  const float* b0    = (const float*)d_in[5];
  const float* g0    = (const float*)d_in[6];
  const float* bt0   = (const float*)d_in[7];
  const float* w1    = (const float*)d_in[8];
  const float* b1    = (const float*)d_in[9];
  const float* g1    = (const float*)d_in[10];
  const float* bt1   = (const float*)d_in[11];
  // d_in[12] = k (always 3, hard-coded)

  char* ws = (char*)d_ws;
  float* stats  = (float*)(ws + WS_STATS);   // sum0,ssq0,sum1,ssq1
  unsigned short* w0b = (unsigned short*)(ws + WS_W0B);
  unsigned short* w1b = (unsigned short*)(ws + WS_W1B);
  float* kw = (float*)(ws + WS_KW);
  int*   ki = (int*)(ws + WS_KI);
  float* PD = (float*)(ws + WS_PD);
  int*   PI = (int*)(ws + WS_PI);
  unsigned short* Y0 = (unsigned short*)(ws + WS_Y0);
  unsigned short* Y1 = (unsigned short*)(ws + WS_BIG);   // reuse (PD/PI dead)

  hipMemsetAsync(stats, 0, 4*256*sizeof(float), stream);
  cvtw_kernel<<<640, 256, 0, stream>>>(w0, w1, w0b, w1b);
  knn_kernel<<<2048, 128, 0, stream>>>(sxyz, oxyz, PD, PI);
  knnmerge_kernel<<<MTOT/256, 256, 0, stream>>>(PD, PI, kw, ki);
  gemm_kernel<CINn, false, true><<<MTOT/128, 256, 0, stream>>>(
      nullptr, w0b, b0, nullptr, nullptr, nullptr, nullptr,
      kw, ki, sfeat, ofeat, Y0, stats, stats + 256);
  gemm_kernel<256, true, false><<<MTOT/128, 256, 0, stream>>>(
      Y0, w1b, b1, stats, stats + 256, g0, bt0,
      nullptr, nullptr, nullptr, nullptr, Y1, stats + 512, stats + 768);
  apply_kernel<<<(MTOT*256)/(256*8), 256, 0, stream>>>(
      Y1, stats + 512, stats + 768, g1, bt1, (float*)d_out);
}

// Round 18
// 221.183 us; speedup vs baseline: 1.0411x; 1.0411x over previous
//
#include <hip/hip_runtime.h>
#include <hip/hip_bf16.h>
#include <cstdint>
#include <cstddef>

// Problem constants (fixed shapes)
#define Bn   4
#define Sn   4096
#define Nn   16384
#define CSn  256
#define COn  128
#define CINn 384
#define MTOT 65536   // B*N

using short8 = short __attribute__((ext_vector_type(8)));
using f32x4  = float __attribute__((ext_vector_type(4)));

static __device__ __forceinline__ float bf2f(unsigned short u){
  unsigned int x = ((unsigned int)u) << 16;
  return __builtin_bit_cast(float, x);
}
static __device__ __forceinline__ unsigned short f2bf(float f){
  unsigned int x = __builtin_bit_cast(unsigned int, f);
  x += 0x7fffu + ((x >> 16) & 1u);   // RNE
  return (unsigned short)(x >> 16);
}

// ---------------- KNN ----------------
static __device__ __forceinline__ void top3_insert(float d, int s,
    float& d0, float& d1, float& d2, int& i0, int& i1, int& i2){
  if (d < d2){
    if (d < d1){
      d2 = d1; i2 = i1;
      if (d < d0){ d1 = d0; i1 = i0; d0 = d; i0 = s; }
      else       { d1 = d;  i1 = s; }
    } else { d2 = d; i2 = s; }
  }
}

// R12/R13-frozen KNN (practical floor ~103us, VALU issue-bound; Q=2 and
// occupancy variants both regressed — R17/R13 A/B evidence).
// 4096 blocks x 128 threads (2 waves), wave-independent, no barriers.
// One 16-instr asm block per key; dist bit-identical to reference chain;
// branch-free top3 strict '<'; ascending slices -> top_k tie-break exact.
__global__ __launch_bounds__(128) void knn_kernel(
    const float* __restrict__ sxyz, const float* __restrict__ oxyz,
    float* __restrict__ PD, int* __restrict__ PI)
{
  __shared__ float4 cb[2][2][64];   // 4 KB: [wave][dbuf][key]

  const int b     = blockIdx.x >> 10;      // 1024 blocks per batch
  const int rem   = blockIdx.x & 1023;
  const int qblk  = rem >> 2;              // 0..255
  const int spair = rem & 3;               // 0..3
  const int lane  = threadIdx.x & 63;
  const int wave  = threadIdx.x >> 6;      // 0..1
  const int gq    = b*Nn + qblk*64 + lane; // global query id [0,65536)
  const float* op = oxyz + (size_t)gq*3;
  const float px = op[0], py = op[1], pz = op[2];
  const float qq = __fadd_rn(__fadd_rn(__fmul_rn(px,px), __fmul_rn(py,py)), __fmul_rn(pz,pz));

  const float* sx = sxyz + (size_t)b*Sn*3;
  const int slice = spair*2 + wave;        // 0..7, ascending key ranges
  const int sbase = slice*512;             // this wave's 512-key chain

  float ax, ay, az;
  {
    int j = sbase + lane;
    ax=sx[j*3+0]; ay=sx[j*3+1]; az=sx[j*3+2];
  }
  {
    float ssv = __fadd_rn(__fadd_rn(__fmul_rn(ax,ax), __fmul_rn(ay,ay)), __fmul_rn(az,az));
    cb[wave][0][lane] = make_float4(ax, ay, az, ssv);
  }

  float d0=3.4e38f, d1=3.4e38f, d2=3.4e38f;
  int   i0=0, i1=0, i2=0;

  int cur = 0;
  for (int c = 0; c < 8; ++c){
    if (c < 7){                          // next chunk's loads EARLY
      int j = sbase + (c+1)*64 + lane;
      ax=sx[j*3+0]; ay=sx[j*3+1]; az=sx[j*3+2];
    }
    const int base = sbase + c*64;
    #pragma unroll 8
    for (int i = 0; i < 64; ++i){
      float4 k = cb[wave][cur][i];       // broadcast ds_read_b128
      float t, u; int t2;
      unsigned long long c0, c1, c2;
      asm("v_mul_f32 %[t], %[kx], %[px]\n\t"
          "v_fma_f32 %[t], %[ky], %[py], %[t]\n\t"
          "v_fma_f32 %[t], %[kz], %[pz], %[t]\n\t"
          "v_add_f32 %[u], %[qq], %[ss]\n\t"
          "v_fma_f32 %[u], -2.0, %[t], %[u]\n\t"
          "v_cmp_lt_f32 %[c0], %[u], %[d0]\n\t"
          "v_cmp_lt_f32 %[c1], %[u], %[d1]\n\t"
          "v_cmp_lt_f32 %[c2], %[u], %[d2]\n\t"
          "v_med3_f32 %[d2], %[u], %[d1], %[d2]\n\t"
          "v_med3_f32 %[d1], %[u], %[d0], %[d1]\n\t"
          "v_min_f32  %[d0], %[u], %[d0]\n\t"
          "v_cndmask_b32 %[t2], %[idx], %[i1], %[c1]\n\t"
          "v_cndmask_b32 %[i2], %[i2], %[t2], %[c2]\n\t"
          "v_cndmask_b32 %[t2], %[idx], %[i0], %[c0]\n\t"
          "v_cndmask_b32 %[i1], %[i1], %[t2], %[c1]\n\t"
          "v_cndmask_b32 %[i0], %[i0], %[idx], %[c0]"
          : [d0]"+v"(d0), [d1]"+v"(d1), [d2]"+v"(d2),
            [i0]"+v"(i0), [i1]"+v"(i1), [i2]"+v"(i2),
            [t]"=&v"(t), [u]"=&v"(u), [t2]"=&v"(t2),
            [c0]"=&s"(c0), [c1]"=&s"(c1), [c2]"=&s"(c2)
          : [kx]"v"(k.x), [ky]"v"(k.y), [kz]"v"(k.z), [ss]"v"(k.w),
            [px]"v"(px), [py]"v"(py), [pz]"v"(pz), [qq]"v"(qq),
            [idx]"v"(base + i));
    }
    if (c < 7){                          // write next chunk AFTER the scan
      int nxt = cur ^ 1;
      float ssv = __fadd_rn(__fadd_rn(__fmul_rn(ax,ax), __fmul_rn(ay,ay)), __fmul_rn(az,az));
      cb[wave][nxt][lane] = make_float4(ax, ay, az, ssv);
      cur = nxt;
    }
  }

  PD[(slice*3+0)*MTOT + gq] = d0;
  PD[(slice*3+1)*MTOT + gq] = d1;
  PD[(slice*3+2)*MTOT + gq] = d2;
  PI[(slice*3+0)*MTOT + gq] = i0;
  PI[(slice*3+1)*MTOT + gq] = i1;
  PI[(slice*3+2)*MTOT + gq] = i2;
}

// merge 8 slice-partials per query (ascending slice = ascending key range,
// strict '<' => reference top_k tie-break), compute weights, write kw/ki.
__global__ __launch_bounds__(256) void knnmerge_kernel(
    const float* __restrict__ PD, const int* __restrict__ PI,
    float* __restrict__ kw, int* __restrict__ ki)
{
  const int gq = blockIdx.x*256 + threadIdx.x;   // 0..65535
  float e0=3.4e38f, e1=3.4e38f, e2=3.4e38f;
  int   j0=0, j1=0, j2=0;
  #pragma unroll
  for (int s = 0; s < 8; ++s){
    #pragma unroll
    for (int j = 0; j < 3; ++j){
      float d = PD[(s*3+j)*MTOT + gq];
      int   i = PI[(s*3+j)*MTOT + gq];
      top3_insert(d, i, e0,e1,e2, j0,j1,j2);
    }
  }
  float wa = 1.0f/(e0+1e-8f), wb = 1.0f/(e1+1e-8f), wc = 1.0f/(e2+1e-8f);
  float sm = __fadd_rn(__fadd_rn(wa, wb), wc);
  size_t base = (size_t)gq*3;
  kw[base+0] = wa/sm; kw[base+1] = wb/sm; kw[base+2] = wc/sm;
  ki[base+0] = j0;    ki[base+1] = j1;    ki[base+2] = j2;
}

// ------------- fp32 -> bf16 weight conversion -------------
__global__ __launch_bounds__(256) void cvtw_kernel(
    const float* __restrict__ w0, const float* __restrict__ w1,
    unsigned short* __restrict__ w0b, unsigned short* __restrict__ w1b)
{
  int i = blockIdx.x*256 + threadIdx.x;
  if (i < 256*384) w0b[i] = f2bf(w0[i]);
  int j = i - 256*384;
  if (j >= 0 && j < 256*256) w1b[j] = f2bf(w1[j]);
}

// ------------- GEMM: Y[M][256] = A[M][KDIM] @ W[256][KDIM]^T + bias ----------
// R13-proven. BM=128, BN=256, BK=64; 4 waves (wave w owns cols [w*64,+64)).
// AFUSE (gemm0): A staged on the fly (kw/ki from LDS, fp32 sfeat gathers):
//   k <  128: A[m][k] = f2bf(ofeat[m][k])
//   k >= 128: A[m][k] = f2bf(fma(w2,s2, fma(w1,s1, mul(w0,s0))))
// BNRELU (gemm1): BN0 scale/shift in-kernel from gemm0 stats, A'=relu(A*sc+sh).
// Epilogue: bf16 store + per-channel sum/sumsq atomics for BN stats.
template<int KDIM, bool BNRELU, bool AFUSE>
__global__ __launch_bounds__(256) void gemm_kernel(
    const unsigned short* __restrict__ A,
    const unsigned short* __restrict__ W,
    const float* __restrict__ bias,
    const float* __restrict__ s0sum,
    const float* __restrict__ s0sq,
    const float* __restrict__ bng,
    const float* __restrict__ bnbt,
    const float* __restrict__ kwg,
    const int*   __restrict__ kig,
    const float* __restrict__ sfeat,
    const float* __restrict__ ofeat,
    unsigned short* __restrict__ Y,
    float* __restrict__ osum,
    float* __restrict__ osq)
{
  __shared__ unsigned short As[128*64];   // 16 KB, XOR-swizzled 16B chunks
  __shared__ unsigned short Bs[256*64];   // 32 KB
  __shared__ float lsc[256], lsh[256];    // BNRELU only
  __shared__ float lkw[128][3];           // AFUSE only
  __shared__ int   lki[128][3];
  const int tid  = threadIdx.x;
  const int lane = tid & 63;
  const int wave = tid >> 6;
  const size_t mbase = (size_t)blockIdx.x * 128;
  if constexpr (BNRELU){
    float mean = s0sum[tid] * (1.0f/65536.0f);
    float var  = s0sq[tid] * (1.0f/65536.0f) - mean*mean;
    float s = bng[tid] / sqrtf(var + 1e-5f);
    lsc[tid] = s;
    lsh[tid] = __fmaf_rn(-mean, s, bnbt[tid]);
  }
  if constexpr (AFUSE){
    float* lkwf = &lkw[0][0];
    int*   lkif = &lki[0][0];
    for (int t = tid; t < 384; t += 256){
      lkwf[t] = kwg[mbase*3 + t];
      lkif[t] = kig[mbase*3 + t];
    }
  }
  f32x4 acc[8][4];
  #pragma unroll
  for (int m2 = 0; m2 < 8; ++m2)
    #pragma unroll
    for (int n2 = 0; n2 < 4; ++n2) acc[m2][n2] = f32x4{0.f,0.f,0.f,0.f};
  __syncthreads();

  for (int k0 = 0; k0 < KDIM; k0 += 64){
    if (k0) __syncthreads();
    // stage A: 128 rows x 8 chunks(16B) = 1024 chunks, 4/thread
    #pragma unroll
    for (int i = 0; i < 4; ++i){
      int cid = tid + 256*i;
      int row = cid >> 3, c8 = cid & 7;
      short8 v;
      if constexpr (AFUSE){
        const int m = (int)mbase + row;
        const int k = k0 + c8*8;
        float vals[8];
        if (k < COn){
          const float4* p = reinterpret_cast<const float4*>(ofeat + (size_t)m*COn + k);
          float4 u0 = p[0], u1 = p[1];
          vals[0]=u0.x; vals[1]=u0.y; vals[2]=u0.z; vals[3]=u0.w;
          vals[4]=u1.x; vals[5]=u1.y; vals[6]=u1.z; vals[7]=u1.w;
        } else {
          const int cc = k - COn;
          const int bb = m >> 14;
          const float* sb = sfeat + (size_t)bb*Sn*CSn;
          const float w0v = lkw[row][0], w1v = lkw[row][1], w2v = lkw[row][2];
          const int   i0  = lki[row][0], i1  = lki[row][1], i2  = lki[row][2];
          const float4* p0 = reinterpret_cast<const float4*>(sb + (size_t)i0*CSn + cc);
          const float4* p1 = reinterpret_cast<const float4*>(sb + (size_t)i1*CSn + cc);
          const float4* p2 = reinterpret_cast<const float4*>(sb + (size_t)i2*CSn + cc);
          float4 a0 = p0[0], a1 = p0[1];
          float4 b0v = p1[0], b1v = p1[1];
          float4 c0v = p2[0], c1v = p2[1];
          float s0[8] = {a0.x,a0.y,a0.z,a0.w,a1.x,a1.y,a1.z,a1.w};
          float s1[8] = {b0v.x,b0v.y,b0v.z,b0v.w,b1v.x,b1v.y,b1v.z,b1v.w};
          float s2[8] = {c0v.x,c0v.y,c0v.z,c0v.w,c1v.x,c1v.y,c1v.z,c1v.w};
          #pragma unroll
          for (int j = 0; j < 8; ++j)
            vals[j] = __fmaf_rn(w2v, s2[j], __fmaf_rn(w1v, s1[j], __fmul_rn(w0v, s0[j])));
        }
        #pragma unroll
        for (int j = 0; j < 8; ++j) v[j] = (short)f2bf(vals[j]);
      } else {
        v = *reinterpret_cast<const short8*>(A + (mbase+row)*KDIM + k0 + c8*8);
        if constexpr (BNRELU){
          #pragma unroll
          for (int j = 0; j < 8; ++j){
            int kc = k0 + c8*8 + j;
            float f = bf2f((unsigned short)v[j]);
            f = fmaxf(__fmaf_rn(f, lsc[kc], lsh[kc]), 0.0f);
            v[j] = (short)f2bf(f);
          }
        }
      }
      *reinterpret_cast<short8*>(reinterpret_cast<char*>(As) + row*128 + ((c8 ^ (row&7)) << 4)) = v;
    }
    // stage B (weights): 256 rows x 8 chunks = 2048 chunks, 8/thread
    #pragma unroll
    for (int i = 0; i < 8; ++i){
      int cid = tid + 256*i;
      int row = cid >> 3, c8 = cid & 7;
      short8 v = *reinterpret_cast<const short8*>(W + (size_t)row*KDIM + k0 + c8*8);
      *reinterpret_cast<short8*>(reinterpret_cast<char*>(Bs) + row*128 + ((c8 ^ (row&7)) << 4)) = v;
    }
    __syncthreads();
    #pragma unroll
    for (int kk = 0; kk < 2; ++kk){
      short8 af[8], bv[4];
      #pragma unroll
      for (int m2 = 0; m2 < 8; ++m2){
        int row = m2*16 + (lane & 15);
        int c8  = kk*4 + (lane >> 4);
        af[m2] = *reinterpret_cast<const short8*>(reinterpret_cast<char*>(As) + row*128 + ((c8 ^ (row&7)) << 4));
      }
      #pragma unroll
      for (int n2 = 0; n2 < 4; ++n2){
        int row = wave*64 + n2*16 + (lane & 15);
        int c8  = kk*4 + (lane >> 4);
        bv[n2] = *reinterpret_cast<const short8*>(reinterpret_cast<char*>(Bs) + row*128 + ((c8 ^ (row&7)) << 4));
      }
      #pragma unroll
      for (int m2 = 0; m2 < 8; ++m2)
        #pragma unroll
        for (int n2 = 0; n2 < 4; ++n2)
          acc[m2][n2] = __builtin_amdgcn_mfma_f32_16x16x32_bf16(af[m2], bv[n2], acc[m2][n2], 0, 0, 0);
    }
  }

  // epilogue: C/D layout col = lane&15, row = (lane>>4)*4 + j  [m89-verified]
  const int colg0 = wave*64;
  float spart[4] = {0,0,0,0}, qpart[4] = {0,0,0,0};
  #pragma unroll
  for (int m2 = 0; m2 < 8; ++m2){
    #pragma unroll
    for (int n2 = 0; n2 < 4; ++n2){
      const int gc  = colg0 + n2*16 + (lane & 15);
      const float bvv = bias[gc];
      #pragma unroll
      for (int j = 0; j < 4; ++j){
        float yv = acc[m2][n2][j] + bvv;
        size_t gr = mbase + m2*16 + (lane>>4)*4 + j;
        Y[gr*256 + gc] = f2bf(yv);
        spart[n2] += yv;
        qpart[n2] = __fmaf_rn(yv, yv, qpart[n2]);
      }
    }
  }
  #pragma unroll
  for (int n2 = 0; n2 < 4; ++n2){
    float s = spart[n2], q = qpart[n2];
    s += __shfl_xor(s, 16); q += __shfl_xor(q, 16);
    s += __shfl_xor(s, 32); q += __shfl_xor(q, 32);
    if (lane < 16){
      int gc = colg0 + n2*16 + lane;
      atomicAdd(&osum[gc], s);
      atomicAdd(&osq[gc], q);
    }
  }
}

// ------------- final BN1 + ReLU -> fp32 out (BN finalize folded in) -------------
__global__ __launch_bounds__(256) void apply_kernel(
    const unsigned short* __restrict__ y,
    const float* __restrict__ s1sum, const float* __restrict__ s1sq,
    const float* __restrict__ g, const float* __restrict__ bt,
    float* __restrict__ out)
{
  __shared__ float ssc[256], ssh[256];
  {
    int c = threadIdx.x;
    float mean = s1sum[c] * (1.0f/65536.0f);
    float var  = s1sq[c] * (1.0f/65536.0f) - mean*mean;
    float s = g[c] / sqrtf(var + 1e-5f);
    ssc[c] = s;
    ssh[c] = __fmaf_rn(-mean, s, bt[c]);
  }
  __syncthreads();
  const int t = blockIdx.x*256 + threadIdx.x;
  const size_t base = (size_t)t * 8;
  const int c0 = (int)(base & 255);
  short8 v = *reinterpret_cast<const short8*>(y + base);
  float r[8];
  #pragma unroll
  for (int j = 0; j < 8; ++j){
    float f = bf2f((unsigned short)v[j]);
    f = __fmaf_rn(f, ssc[c0+j], ssh[c0+j]);
    r[j] = fmaxf(f, 0.0f);
  }
  float4 o0, o1;
  o0.x=r[0]; o0.y=r[1]; o0.z=r[2]; o0.w=r[3];
  o1.x=r[4]; o1.y=r[5]; o1.z=r[6]; o1.w=r[7];
  *reinterpret_cast<float4*>(out + base)     = o0;
  *reinterpret_cast<float4*>(out + base + 4) = o1;
}

// ---------------- workspace layout ----------------
constexpr size_t WS_STATS = 0;                                  // 4*256 f32
constexpr size_t WS_W0B   = 8192;                               // 98304 bf16
constexpr size_t WS_W1B   = WS_W0B + 196608;                    // 65536 bf16
constexpr size_t WS_KW    = WS_W1B + 131072;                    // M*3 f32
constexpr size_t WS_KI    = WS_KW + 786432;                     // M*3 i32
constexpr size_t WS_BIG   = 4194304;                            // big region
constexpr size_t WS_Y0    = WS_BIG + (size_t)MTOT*CINn*2;       // M*256 bf16
// PD/PI (6.3 MB each) at BIG start; dead after knnmerge. Y1 reuses BIG start.
constexpr size_t WS_PD    = WS_BIG;
constexpr size_t WS_PI    = WS_BIG + (size_t)8*3*MTOT*4;

extern "C" void kernel_launch(void* const* d_in, const int* in_sizes, int n_in,
                              void* d_out, int out_size, void* d_ws, size_t ws_size,
                              hipStream_t stream)
{
  const float* sxyz  = (const float*)d_in[0];
  const float* sfeat = (const float*)d_in[1];
  const float* oxyz  = (const float*)d_in[2];
  const float* ofeat = (const float*)d_in[3];
  const float* w0    = (const float*)d_in[4];
  const float* b0    = (const float*)d_in[5];
  const float* g0    = (const float*)d_in[6];
  const float* bt0   = (const float*)d_in[7];
  const float* w1    = (const float*)d_in[8];
  const float* b1    = (const float*)d_in[9];
  const float* g1    = (const float*)d_in[10];
  const float* bt1   = (const float*)d_in[11];
  // d_in[12] = k (always 3, hard-coded)

  char* ws = (char*)d_ws;
  float* stats  = (float*)(ws + WS_STATS);   // sum0,ssq0,sum1,ssq1
  unsigned short* w0b = (unsigned short*)(ws + WS_W0B);
  unsigned short* w1b = (unsigned short*)(ws + WS_W1B);
  float* kw = (float*)(ws + WS_KW);
  int*   ki = (int*)(ws + WS_KI);
  float* PD = (float*)(ws + WS_PD);
  int*   PI = (int*)(ws + WS_PI);
  unsigned short* Y0 = (unsigned short*)(ws + WS_Y0);
  unsigned short* Y1 = (unsigned short*)(ws + WS_BIG);   // reuse (PD/PI dead)

  hipMemsetAsync(stats, 0, 4*256*sizeof(float), stream);
  cvtw_kernel<<<640, 256, 0, stream>>>(w0, w1, w0b, w1b);
  knn_kernel<<<4096, 128, 0, stream>>>(sxyz, oxyz, PD, PI);
  knnmerge_kernel<<<MTOT/256, 256, 0, stream>>>(PD, PI, kw, ki);
  gemm_kernel<CINn, false, true><<<MTOT/128, 256, 0, stream>>>(
      nullptr, w0b, b0, nullptr, nullptr, nullptr, nullptr,
      kw, ki, sfeat, ofeat, Y0, stats, stats + 256);
  gemm_kernel<256, true, false><<<MTOT/128, 256, 0, stream>>>(
      Y0, w1b, b1, stats, stats + 256, g0, bt0,
      nullptr, nullptr, nullptr, nullptr, Y1, stats + 512, stats + 768);
  apply_kernel<<<(MTOT*256)/(256*8), 256, 0, stream>>>(
      Y1, stats + 512, stats + 768, g1, bt1, (float*)d_out);
}